// Round 9
// baseline (261.150 us; speedup 1.0000x reference)
//
#include <hip/hip_runtime.h>
#include <hip/hip_bf16.h>

typedef short s8v __attribute__((ext_vector_type(8)));   // 8 bf16 = 16B (4 VGPR)
typedef float f4v __attribute__((ext_vector_type(4)));   // MFMA accum

#define MFMA_BF16(a, b, c) __builtin_amdgcn_mfma_f32_16x16x32_bf16((a), (b), (c), 0, 0, 0)

// async global->LDS, 16B per lane; LDS dest = wave-uniform base + lane*16
#define GLDS16(g, l) __builtin_amdgcn_global_load_lds( \
    (const __attribute__((address_space(1))) void*)(g), \
    (__attribute__((address_space(3))) void*)(l), 16, 0, 0)

__device__ __forceinline__ short f2bf(float f) {
  __hip_bfloat16 h = __float2bfloat16(f);
  return *reinterpret_cast<short*>(&h);
}
__device__ __forceinline__ float bf2f(short s) {
  __hip_bfloat16 h;
  *reinterpret_cast<short*>(&h) = s;
  return __bfloat162float(h);
}

// ---------------- fp32 -> bf16 conversion ----------------
__global__ __launch_bounds__(256) void cvt_kernel(const float* __restrict__ in,
                                                  short* __restrict__ out, int n8) {
  int i = blockIdx.x * 256 + threadIdx.x;
  if (i >= n8) return;
  const float* p = in + (size_t)i * 8;
  float4 a = *(const float4*)p;
  float4 b = *(const float4*)(p + 4);
  s8v o;
  o[0] = f2bf(a.x); o[1] = f2bf(a.y); o[2] = f2bf(a.z); o[3] = f2bf(a.w);
  o[4] = f2bf(b.x); o[5] = f2bf(b.y); o[6] = f2bf(b.z); o[7] = f2bf(b.w);
  *(s8v*)(out + (size_t)i * 8) = o;
}

// ------- 8-phase 256x256 GEMM core (m201-style), BK=64, 8 waves -------------
// A row-major [M][ASTR] over K; B row-major [N][BSTR] over K (B^T layout).
// LDS 128KB: 2 bufs x 4 half-tile regions (A0,A1,B0,B1) x 16KB.
// Per K-tile v: 4 phases (quadrants). Each phase stages ONE half-tile of tile
// v+1 into buf[(v+1)&1] (its last reader, tile v-1, is barrier-complete).
// vmcnt(2) only at ph0 (tile v's 8 loads landed; the stage just issued stays
// in flight); vmcnt(0) only at the final tile. ph0 ds_reads AFTER the barrier
// (cross-wave staging proven there); ph1-3 before it. lgkmcnt(0)+setprio MFMA.
// XOR swizzle (row&7)<<4 on per-lane global source AND ds_read addr (rule 21).
template<int KT, int ASTR, int BSTR>
__device__ __forceinline__ void mm8_core(const short* __restrict__ Ab,
                                         const short* __restrict__ Bb,
                                         char* lds, f4v (&acc)[8][4]) {
  const int t = threadIdx.x;              // 0..511
  const int lane = t & 63, wv = t >> 6;
  const int wm = wv >> 2, wn = wv & 3;    // wave tile: rows wm*128, cols wn*64
  const int lr = lane & 15, lg = lane >> 4;

  const int srow = t >> 3;                // staging row 0..63 (+64 round 2)
  const int scolb = (t & 7) * 16;         // byte col within 128B row
  const int sswz = scolb ^ ((srow & 7) << 4);

  // stage half-tile h (0=A0,1=A1,2=B0,3=B1) of K-tile tt into buf[tt&1]
  auto stageH = [&](int tt, int h) {
    const short* src = (h < 2) ? Ab : Bb;
    const int str = (h < 2) ? ASTR : BSTR;
    const int rbase = (h & 1) * 128;
    char* dst = lds + (tt & 1) * 65536 + h * 16384;
    #pragma unroll
    for (int j = 0; j < 2; ++j) {
      int row = srow + j * 64;
      GLDS16((const char*)(src + (size_t)(rbase + row) * str + tt * 64) + sswz,
             dst + row * 128 + scolb);
    }
  };

  // prologue: tile 0 fully staged (8 loads)
  stageH(0, 0); stageH(0, 1); stageH(0, 2); stageH(0, 3);

  for (int v = 0; v < KT; ++v) {
    const char* buf = lds + (v & 1) * 65536;
    const char* regA = buf + wm * 16384;                 // this wave's A-half
    const char* regB = buf + 32768 + (wn >> 1) * 16384;  // this wave's B-half
    const int brow = (wn & 1) * 64;
    s8v af[4][2], bf[2][2];
    #pragma unroll
    for (int ph = 0; ph < 4; ++ph) {
      const int mq = ph >> 1, nq = ph & 1;
      if (v + 1 < KT) stageH(v + 1, ph);   // prefetch next tile, other buffer
      if (ph == 0) {
        if (v + 1 < KT) asm volatile("s_waitcnt vmcnt(2)" ::: "memory");
        else            asm volatile("s_waitcnt vmcnt(0)" ::: "memory");
        __builtin_amdgcn_s_barrier();      // all waves' vmcnt passed: tile v ready
      }
      if (nq == 0) {                       // A frags change at ph0, ph2
        #pragma unroll
        for (int mf = 0; mf < 4; ++mf)
          #pragma unroll
          for (int kk = 0; kk < 2; ++kk)
            af[mf][kk] = *(const s8v*)(regA + (mq * 64 + mf * 16 + lr) * 128 +
                                       ((kk * 64 + lg * 16) ^ ((lr & 7) << 4)));
      }
      #pragma unroll
      for (int nf = 0; nf < 2; ++nf)
        #pragma unroll
        for (int kk = 0; kk < 2; ++kk)
          bf[nf][kk] = *(const s8v*)(regB + (brow + nq * 32 + nf * 16 + lr) * 128 +
                                     ((kk * 64 + lg * 16) ^ ((lr & 7) << 4)));
      if (ph != 0) __builtin_amdgcn_s_barrier();
      asm volatile("s_waitcnt lgkmcnt(0)" ::: "memory");
      __builtin_amdgcn_s_setprio(1);
      #pragma unroll
      for (int kk = 0; kk < 2; ++kk)
        #pragma unroll
        for (int mf = 0; mf < 4; ++mf)
          #pragma unroll
          for (int nf = 0; nf < 2; ++nf)
            acc[mq * 4 + mf][nq * 2 + nf] =
                MFMA_BF16(af[mf][kk], bf[nf][kk], acc[mq * 4 + mf][nq * 2 + nf]);
      __builtin_amdgcn_s_setprio(0);
      __builtin_amdgcn_s_barrier();
    }
  }
}

// ---------------- projections: y = x @ W^T + b ----------------
__global__ __launch_bounds__(512, 1) void proj_kernel(
    const short* __restrict__ xb, const short* __restrict__ wb,
    const float* __restrict__ bq, const float* __restrict__ bk, const float* __restrict__ bv,
    short* __restrict__ qo, short* __restrict__ ko, short* __restrict__ vo) {
  const int bx = blockIdx.x;
  const int L = (bx & 7) * 96 + (bx >> 3);    // bijective XCD swizzle (768 = 8*96)
  const int cb = L & 1, rbm = L >> 1;
  const int mat = rbm >> 7, rb = rbm & 127;
  const int R0 = rb * 256, C0 = cb * 256;
  const float* bias = (mat == 0) ? bq : (mat == 1) ? bk : bv;
  short* out = (mat == 0) ? qo : (mat == 1) ? ko : vo;

  __shared__ short lds[65536];   // 128 KB
  f4v acc[8][4];
  #pragma unroll
  for (int i = 0; i < 8; i++)
    #pragma unroll
    for (int j = 0; j < 4; j++) acc[i][j] = (f4v){0.f, 0.f, 0.f, 0.f};

  mm8_core<8, 512, 512>(xb + (size_t)R0 * 512,
                        wb + (size_t)mat * 512 * 512 + (size_t)C0 * 512,
                        (char*)lds, acc);

  const int lane = threadIdx.x & 63, wv = threadIdx.x >> 6;
  const int wm = wv >> 2, wn = wv & 3;
  const int lr = lane & 15, lg = lane >> 4;
  #pragma unroll
  for (int nf = 0; nf < 4; ++nf) {
    int col = C0 + wn * 64 + nf * 16 + lr;
    float bb = bias[col];
    #pragma unroll
    for (int mf = 0; mf < 8; ++mf)
      #pragma unroll
      for (int i = 0; i < 4; i++) {
        int row = R0 + wm * 128 + mf * 16 + lg * 4 + i;
        out[(size_t)row * 512 + col] = f2bf(acc[mf][nf][i] + bb);
      }
  }
}

// ---------------- v (B,C,N) -> v_t (B,N,C) ----------------
__global__ __launch_bounds__(256) void transpose_kernel(const short* __restrict__ v,
                                                        short* __restrict__ vt) {
  const int nb = blockIdx.x;
  const int cbk = blockIdx.y;
  const int b = blockIdx.z;
  __shared__ short tile[64 * 72];
  const int t = threadIdx.x;
  const int r = t >> 2, qd = t & 3;
  const short* src = v + (size_t)(b * 1024 + cbk * 64 + r) * 512 + nb * 64 + qd * 16;
  s8v v0 = *(const s8v*)src;
  s8v v1 = *(const s8v*)(src + 8);
  *(s8v*)&tile[r * 72 + qd * 16] = v0;
  *(s8v*)&tile[r * 72 + qd * 16 + 8] = v1;
  __syncthreads();
  s8v o0, o1;
  #pragma unroll
  for (int j = 0; j < 8; j++) o0[j] = tile[(qd * 16 + j) * 72 + r];
  #pragma unroll
  for (int j = 0; j < 8; j++) o1[j] = tile[(qd * 16 + 8 + j) * 72 + r];
  short* dst = vt + (size_t)(b * 512 + nb * 64 + r) * 1024 + cbk * 64 + qd * 16;
  *(s8v*)dst = o0;
  *(s8v*)(dst + 8) = o1;
}

// ---------------- E = Q @ K^T per batch ----------------
__global__ __launch_bounds__(512, 1) void qk_kernel(const short* __restrict__ qb,
                                                    const short* __restrict__ kb,
                                                    short* __restrict__ eb) {
  const int bx = blockIdx.x;
  const int L = (bx & 7) * 64 + (bx >> 3);    // 512 = 8*64
  const int cb = L & 3, rbb = L >> 2;
  const int rb = rbb & 3, b = rbb >> 2;
  const int R0 = rb * 256, C0 = cb * 256;

  __shared__ short lds[65536];
  f4v acc[8][4];
  #pragma unroll
  for (int i = 0; i < 8; i++)
    #pragma unroll
    for (int j = 0; j < 4; j++) acc[i][j] = (f4v){0.f, 0.f, 0.f, 0.f};

  mm8_core<8, 512, 512>(qb + (size_t)(b * 1024 + R0) * 512,
                        kb + (size_t)(b * 1024 + C0) * 512, (char*)lds, acc);

  const int lane = threadIdx.x & 63, wv = threadIdx.x >> 6;
  const int wm = wv >> 2, wn = wv & 3;
  const int lr = lane & 15, lg = lane >> 4;
  #pragma unroll
  for (int nf = 0; nf < 4; ++nf) {
    int col = C0 + wn * 64 + nf * 16 + lr;
    #pragma unroll
    for (int mf = 0; mf < 8; ++mf)
      #pragma unroll
      for (int i = 0; i < 4; i++) {
        int row = R0 + wm * 128 + mf * 16 + lg * 4 + i;
        eb[(size_t)(b * 1024 + row) * 1024 + col] = f2bf(acc[mf][nf][i]);
      }
  }
}

// ---------------- in-place row softmax (rows of 1024 bf16) ----------------
__global__ __launch_bounds__(256) void softmax_kernel(short* __restrict__ eb) {
  const int row = blockIdx.x * 4 + (threadIdx.x >> 6);
  const int lane = threadIdx.x & 63;
  short* p = eb + (size_t)row * 1024 + lane * 16;
  s8v a = *(const s8v*)p;
  s8v bvv = *(const s8v*)(p + 8);
  float v[16];
  #pragma unroll
  for (int j = 0; j < 8; j++) { v[j] = bf2f(a[j]); v[8 + j] = bf2f(bvv[j]); }
  float m = v[0];
  #pragma unroll
  for (int j = 1; j < 16; j++) m = fmaxf(m, v[j]);
  #pragma unroll
  for (int s = 1; s <= 32; s <<= 1) m = fmaxf(m, __shfl_xor(m, s));
  float l = 0.f;
  #pragma unroll
  for (int j = 0; j < 16; j++) { v[j] = __expf(v[j] - m); l += v[j]; }
  #pragma unroll
  for (int s = 1; s <= 32; s <<= 1) l += __shfl_xor(l, s);
  const float inv = 1.0f / l;
  s8v o0, o1;
  #pragma unroll
  for (int j = 0; j < 8; j++) { o0[j] = f2bf(v[j] * inv); o1[j] = f2bf(v[8 + j] * inv); }
  *(s8v*)p = o0;
  *(s8v*)(p + 8) = o1;
}

// ---------------- out = beta * (P @ V) + v ----------------
__global__ __launch_bounds__(512, 1) void pv_kernel(const short* __restrict__ eb,
                                                    const short* __restrict__ vt,
                                                    const short* __restrict__ vb,
                                                    const float* __restrict__ beta_p,
                                                    float* __restrict__ outp) {
  const int bx = blockIdx.x;
  const int L = (bx & 7) * 32 + (bx >> 3);    // 256 = 8*32
  const int cb = L & 1, rbb = L >> 1;
  const int rb = rbb & 3, b = rbb >> 2;
  const int R0 = rb * 256, C0 = cb * 256;

  __shared__ short lds[65536];
  f4v acc[8][4];
  #pragma unroll
  for (int i = 0; i < 8; i++)
    #pragma unroll
    for (int j = 0; j < 4; j++) acc[i][j] = (f4v){0.f, 0.f, 0.f, 0.f};

  mm8_core<16, 1024, 1024>(eb + (size_t)(b * 1024 + R0) * 1024,
                           vt + (size_t)(b * 512 + C0) * 1024, (char*)lds, acc);

  const float beta = beta_p[0];
  const int lane = threadIdx.x & 63, wv = threadIdx.x >> 6;
  const int wm = wv >> 2, wn = wv & 3;
  const int lr = lane & 15, lg = lane >> 4;
  #pragma unroll
  for (int nf = 0; nf < 4; ++nf) {
    int col = C0 + wn * 64 + nf * 16 + lr;
    #pragma unroll
    for (int mf = 0; mf < 8; ++mf)
      #pragma unroll
      for (int i = 0; i < 4; i++) {
        int row = R0 + wm * 128 + mf * 16 + lg * 4 + i;
        float val = beta * acc[mf][nf][i] +
                    bf2f(vb[(size_t)(b * 1024 + row) * 512 + col]);
        outp[(size_t)(b * 1024 + row) * 512 + col] = val;
      }
  }
}

extern "C" void kernel_launch(void* const* d_in, const int* in_sizes, int n_in,
                              void* d_out, int out_size, void* d_ws, size_t ws_size,
                              hipStream_t stream) {
  (void)in_sizes; (void)n_in; (void)out_size; (void)ws_size;
  const float* x = (const float*)d_in[0];
  const float* Wq = (const float*)d_in[1];
  const float* bq = (const float*)d_in[2];
  const float* Wk = (const float*)d_in[3];
  const float* bk = (const float*)d_in[4];
  const float* Wv = (const float*)d_in[5];
  const float* bv = (const float*)d_in[6];
  const float* beta = (const float*)d_in[7];
  float* out = (float*)d_out;

  char* ws = (char*)d_ws;
  short* xb = (short*)(ws);                  // 32MB, reused as v_t after proj
  short* wb = (short*)(ws + 33554432);       // 1.5MB
  short* qb = (short*)(ws + 35127296);       // 32MB
  short* kb = (short*)(ws + 68681728);       // 32MB
  short* vb = (short*)(ws + 102236160);      // 32MB
  short* eb = (short*)(ws + 135790592);      // 64MB (E, then P in-place)
  short* vt = xb;

  cvt_kernel<<<8192, 256, 0, stream>>>(x, xb, 2097152);
  cvt_kernel<<<128, 256, 0, stream>>>(Wq, wb, 32768);
  cvt_kernel<<<128, 256, 0, stream>>>(Wk, wb + 262144, 32768);
  cvt_kernel<<<128, 256, 0, stream>>>(Wv, wb + 524288, 32768);
  proj_kernel<<<768, 512, 0, stream>>>(xb, wb, bq, bk, bv, qb, kb, vb);
  transpose_kernel<<<dim3(8, 16, 32), 256, 0, stream>>>(vb, vt);
  qk_kernel<<<512, 512, 0, stream>>>(qb, kb, eb);
  softmax_kernel<<<8192, 256, 0, stream>>>(eb);
  pv_kernel<<<256, 512, 0, stream>>>(eb, vt, vb, beta, out);
}

// Round 10
// 239.271 us; speedup vs baseline: 1.0914x; 1.0914x over previous
//
#include <hip/hip_runtime.h>
#include <hip/hip_bf16.h>

typedef short s8v __attribute__((ext_vector_type(8)));   // 8 bf16 = 16B (4 VGPR)
typedef float f4v __attribute__((ext_vector_type(4)));   // MFMA accum

#define MFMA_BF16(a, b, c) __builtin_amdgcn_mfma_f32_16x16x32_bf16((a), (b), (c), 0, 0, 0)

// async global->LDS, 16B per lane; LDS dest = wave-uniform base + lane*16
#define GLDS16(g, l) __builtin_amdgcn_global_load_lds( \
    (const __attribute__((address_space(1))) void*)(g), \
    (__attribute__((address_space(3))) void*)(l), 16, 0, 0)

__device__ __forceinline__ short f2bf(float f) {
  __hip_bfloat16 h = __float2bfloat16(f);
  return *reinterpret_cast<short*>(&h);
}
__device__ __forceinline__ float bf2f(short s) {
  __hip_bfloat16 h;
  *reinterpret_cast<short*>(&h) = s;
  return __bfloat162float(h);
}

// ---------------- fp32 -> bf16 conversion (x) ----------------
__global__ __launch_bounds__(256) void cvt_kernel(const float* __restrict__ in,
                                                  short* __restrict__ out, int n8) {
  int i = blockIdx.x * 256 + threadIdx.x;
  if (i >= n8) return;
  const float* p = in + (size_t)i * 8;
  float4 a = *(const float4*)p;
  float4 b = *(const float4*)(p + 4);
  s8v o;
  o[0] = f2bf(a.x); o[1] = f2bf(a.y); o[2] = f2bf(a.z); o[3] = f2bf(a.w);
  o[4] = f2bf(b.x); o[5] = f2bf(b.y); o[6] = f2bf(b.z); o[7] = f2bf(b.w);
  *(s8v*)(out + (size_t)i * 8) = o;
}

// ---------------- fp32 -> bf16 for the three W in one launch ----------------
__global__ __launch_bounds__(256) void cvt_w_kernel(const float* __restrict__ Wq,
                                                    const float* __restrict__ Wk,
                                                    const float* __restrict__ Wv,
                                                    short* __restrict__ out) {
  int i = blockIdx.x * 256 + threadIdx.x;      // 0..98303
  int mat = i >> 15, idx = i & 32767;          // 32768 groups of 8 per matrix
  const float* src = (mat == 0) ? Wq : (mat == 1) ? Wk : Wv;
  const float* p = src + (size_t)idx * 8;
  float4 a = *(const float4*)p;
  float4 b = *(const float4*)(p + 4);
  s8v o;
  o[0] = f2bf(a.x); o[1] = f2bf(a.y); o[2] = f2bf(a.z); o[3] = f2bf(a.w);
  o[4] = f2bf(b.x); o[5] = f2bf(b.y); o[6] = f2bf(b.z); o[7] = f2bf(b.w);
  *(s8v*)(out + (size_t)mat * 262144 + (size_t)idx * 8) = o;
}

// ------- 128x128 GEMM core, BK=64, 4 waves, 2-buffer ring, counted vmcnt ----
// (byte-identical schedule to R8: vmcnt(8) keeps next tile's 8 loads in
// flight; mid-tile lgkmcnt(0)+barrier frees buffer for stage(t+2);
// 2 blocks/CU supply cross-block TLP; XOR swizzle both-sides, 0 conflicts.)
template<int KSTEPS, int ASTR, int BSTR>
__device__ __forceinline__ void mm_core(const short* __restrict__ Abase,
                                        const short* __restrict__ Bbase,
                                        short* As0, short* Bs0,
                                        short* As1, short* Bs1,
                                        f4v (&acc)[4][4]) {
  const int t = threadIdx.x;
  const int lane = t & 63, w = t >> 6;
  const int lr = lane & 15, lg = lane >> 4;
  const int wr = (w >> 1) * 64, wc = (w & 1) * 64;
  const int srcc = ((lane & 7) * 16) ^ ((lane >> 3) << 4);  // swizzled src col byte
  const int rstage = w * 32 + (lane >> 3);

  auto stage = [&](short* As, short* Bs, int kt) {
    #pragma unroll
    for (int j = 0; j < 4; ++j)
      GLDS16((const char*)(Abase + (size_t)(rstage + j * 8) * ASTR) + kt * 128 + srcc,
             (char*)As + (w * 32 + j * 8) * 128);
    #pragma unroll
    for (int j = 0; j < 4; ++j)
      GLDS16((const char*)(Bbase + (size_t)(rstage + j * 8) * BSTR) + kt * 128 + srcc,
             (char*)Bs + (w * 32 + j * 8) * 128);
  };

  stage(As0, Bs0, 0);
  if (KSTEPS > 1) stage(As1, Bs1, 1);
  short* Asc = As0; short* Bsc = Bs0;
  short* Asn = As1; short* Bsn = Bs1;

  for (int kt = 0; kt < KSTEPS; ++kt) {
    if (kt + 1 < KSTEPS) asm volatile("s_waitcnt vmcnt(8)" ::: "memory");
    else                 asm volatile("s_waitcnt vmcnt(0)" ::: "memory");
    __builtin_amdgcn_s_barrier();
    #pragma unroll
    for (int kk = 0; kk < 2; ++kk) {
      s8v af[4], bfr[4];
      #pragma unroll
      for (int mf = 0; mf < 4; ++mf)
        af[mf] = *(const s8v*)((const char*)Asc + (wr + mf * 16 + lr) * 128 +
                               ((kk * 64 + lg * 16) ^ ((lr & 7) << 4)));
      #pragma unroll
      for (int nf = 0; nf < 4; ++nf)
        bfr[nf] = *(const s8v*)((const char*)Bsc + (wc + nf * 16 + lr) * 128 +
                                ((kk * 64 + lg * 16) ^ ((lr & 7) << 4)));
      if (kk == 1) {
        asm volatile("s_waitcnt lgkmcnt(0)" ::: "memory");
        __builtin_amdgcn_s_barrier();
        if (kt + 2 < KSTEPS) stage(Asc, Bsc, kt + 2);
      }
      __builtin_amdgcn_s_setprio(1);
      #pragma unroll
      for (int mf = 0; mf < 4; ++mf)
        #pragma unroll
        for (int nf = 0; nf < 4; ++nf)
          acc[mf][nf] = MFMA_BF16(af[mf], bfr[nf], acc[mf][nf]);
      __builtin_amdgcn_s_setprio(0);
    }
    short* ta = Asc; Asc = Asn; Asn = ta;
    short* tb = Bsc; Bsc = Bsn; Bsn = tb;
  }
}

// ---------------- projections: y = x @ W^T + b (+ fused V-transpose) --------
__global__ __launch_bounds__(256) void proj_kernel(
    const short* __restrict__ xb, const short* __restrict__ wb,
    const float* __restrict__ bq, const float* __restrict__ bk, const float* __restrict__ bv,
    short* __restrict__ qo, short* __restrict__ ko, short* __restrict__ vo,
    short* __restrict__ vt, int fuse) {
  const int bx = blockIdx.x;
  const int L = (bx & 7) * 384 + (bx >> 3);   // bijective XCD swizzle (3072 = 8*384)
  const int cb = L & 3, rb = (L >> 2) & 255, mat = L >> 10;
  const int R0 = rb * 128, C0 = cb * 128;
  const float* bias = (mat == 0) ? bq : (mat == 1) ? bk : bv;
  short* out = (mat == 0) ? qo : (mat == 1) ? ko : vo;

  __shared__ short smem[32768];   // 64KB: 4 x 16KB staging; reused for transpose
  short* As0 = smem;
  short* Bs0 = smem + 8192;
  short* As1 = smem + 16384;
  short* Bs1 = smem + 24576;

  f4v acc[4][4];
  #pragma unroll
  for (int i = 0; i < 4; i++)
    #pragma unroll
    for (int j = 0; j < 4; j++) acc[i][j] = (f4v){0.f, 0.f, 0.f, 0.f};

  mm_core<8, 512, 512>(xb + (size_t)R0 * 512,
                       wb + (size_t)mat * 512 * 512 + (size_t)C0 * 512,
                       As0, Bs0, As1, Bs1, acc);

  const int lane = threadIdx.x & 63, w = threadIdx.x >> 6;
  const int lr = lane & 15, lg = lane >> 4;
  const int wr = (w >> 1) * 64, wc = (w & 1) * 64;
  const bool dovt = (mat == 2) && (fuse != 0);
  // after mm_core's final barrier all LDS reads are complete -> smem reusable
  short* lds_t = smem;   // [n_local 0..127][c_local 0..127], stride 136 shorts
  #pragma unroll
  for (int nf = 0; nf < 4; ++nf) {
    int col = C0 + wc + nf * 16 + lr;
    float bb = bias[col];
    #pragma unroll
    for (int mf = 0; mf < 4; ++mf)
      #pragma unroll
      for (int i = 0; i < 4; i++) {
        int rloc = wr + mf * 16 + lg * 4 + i;
        short bv16 = f2bf(acc[mf][nf][i] + bb);
        out[(size_t)(R0 + rloc) * 512 + col] = bv16;
        if (dovt) lds_t[(wc + nf * 16 + lr) * 136 + rloc] = bv16;
      }
  }
  if (dovt) {
    __syncthreads();
    const int b = R0 >> 10, c0 = R0 & 1023;
    const int n_l = threadIdx.x >> 1, ch = (threadIdx.x & 1) * 64;
    const short* srcp = lds_t + n_l * 136 + ch;
    short* dstp = vt + ((size_t)(b * 512 + C0 + n_l)) * 1024 + c0 + ch;
    #pragma unroll
    for (int j = 0; j < 8; ++j) *(s8v*)(dstp + j * 8) = *(const s8v*)(srcp + j * 8);
  }
}

// ---------------- v (B,C,N) -> v_t (B,N,C)  (fallback path) ----------------
__global__ __launch_bounds__(256) void transpose_kernel(const short* __restrict__ v,
                                                        short* __restrict__ vt) {
  const int nb = blockIdx.x;
  const int cbk = blockIdx.y;
  const int b = blockIdx.z;
  __shared__ short tile[64 * 72];
  const int t = threadIdx.x;
  const int r = t >> 2, qd = t & 3;
  const short* src = v + (size_t)(b * 1024 + cbk * 64 + r) * 512 + nb * 64 + qd * 16;
  s8v v0 = *(const s8v*)src;
  s8v v1 = *(const s8v*)(src + 8);
  *(s8v*)&tile[r * 72 + qd * 16] = v0;
  *(s8v*)&tile[r * 72 + qd * 16 + 8] = v1;
  __syncthreads();
  s8v o0, o1;
  #pragma unroll
  for (int j = 0; j < 8; j++) o0[j] = tile[(qd * 16 + j) * 72 + r];
  #pragma unroll
  for (int j = 0; j < 8; j++) o1[j] = tile[(qd * 16 + 8 + j) * 72 + r];
  short* dst = vt + (size_t)(b * 512 + nb * 64 + r) * 1024 + cbk * 64 + qd * 16;
  *(s8v*)dst = o0;
  *(s8v*)(dst + 8) = o1;
}

// ---------------- E = Q @ K^T per batch ----------------
__global__ __launch_bounds__(256) void qk_kernel(const short* __restrict__ qb,
                                                 const short* __restrict__ kb,
                                                 short* __restrict__ eb) {
  const int bx = blockIdx.x;
  const int L = (bx & 7) * 256 + (bx >> 3);   // 2048 = 8*256
  const int rb = L & 7, cb = (L >> 3) & 7, b = L >> 6;
  const int R0 = rb * 128, C0 = cb * 128;

  __shared__ short As0[8192], Bs0[8192], As1[8192], Bs1[8192];
  f4v acc[4][4];
  #pragma unroll
  for (int i = 0; i < 4; i++)
    #pragma unroll
    for (int j = 0; j < 4; j++) acc[i][j] = (f4v){0.f, 0.f, 0.f, 0.f};

  mm_core<8, 512, 512>(qb + (size_t)(b * 1024 + R0) * 512,
                       kb + (size_t)(b * 1024 + C0) * 512,
                       As0, Bs0, As1, Bs1, acc);

  const int lane = threadIdx.x & 63, w = threadIdx.x >> 6;
  const int lr = lane & 15, lg = lane >> 4;
  const int wr = (w >> 1) * 64, wc = (w & 1) * 64;
  #pragma unroll
  for (int nf = 0; nf < 4; ++nf) {
    int col = C0 + wc + nf * 16 + lr;
    #pragma unroll
    for (int mf = 0; mf < 4; ++mf)
      #pragma unroll
      for (int i = 0; i < 4; i++) {
        int row = R0 + wr + mf * 16 + lg * 4 + i;
        eb[(size_t)(b * 1024 + row) * 1024 + col] = f2bf(acc[mf][nf][i]);
      }
  }
}

// ---------------- in-place row softmax (rows of 1024 bf16) ----------------
__global__ __launch_bounds__(256) void softmax_kernel(short* __restrict__ eb) {
  const int row = blockIdx.x * 4 + (threadIdx.x >> 6);
  const int lane = threadIdx.x & 63;
  short* p = eb + (size_t)row * 1024 + lane * 16;
  s8v a = *(const s8v*)p;
  s8v bvv = *(const s8v*)(p + 8);
  float v[16];
  #pragma unroll
  for (int j = 0; j < 8; j++) { v[j] = bf2f(a[j]); v[8 + j] = bf2f(bvv[j]); }
  float m = v[0];
  #pragma unroll
  for (int j = 1; j < 16; j++) m = fmaxf(m, v[j]);
  #pragma unroll
  for (int s = 1; s <= 32; s <<= 1) m = fmaxf(m, __shfl_xor(m, s));
  float l = 0.f;
  #pragma unroll
  for (int j = 0; j < 16; j++) { v[j] = __expf(v[j] - m); l += v[j]; }
  #pragma unroll
  for (int s = 1; s <= 32; s <<= 1) l += __shfl_xor(l, s);
  const float inv = 1.0f / l;
  s8v o0, o1;
  #pragma unroll
  for (int j = 0; j < 8; j++) { o0[j] = f2bf(v[j] * inv); o1[j] = f2bf(v[8 + j] * inv); }
  *(s8v*)p = o0;
  *(s8v*)(p + 8) = o1;
}

// ---------------- out = beta * (P @ V) + v ----------------
__global__ __launch_bounds__(256) void pv_kernel(const short* __restrict__ eb,
                                                 const short* __restrict__ vt,
                                                 const short* __restrict__ vb,
                                                 const float* __restrict__ beta_p,
                                                 float* __restrict__ outp) {
  const int bx = blockIdx.x;
  const int L = (bx & 7) * 128 + (bx >> 3);   // 1024 = 8*128
  const int cb = L & 3, rb = (L >> 2) & 7, b = L >> 5;
  const int R0 = rb * 128, C0 = cb * 128;

  __shared__ short As0[8192], Bs0[8192], As1[8192], Bs1[8192];
  f4v acc[4][4];
  #pragma unroll
  for (int i = 0; i < 4; i++)
    #pragma unroll
    for (int j = 0; j < 4; j++) acc[i][j] = (f4v){0.f, 0.f, 0.f, 0.f};

  mm_core<16, 1024, 1024>(eb + (size_t)(b * 1024 + R0) * 1024,
                          vt + (size_t)(b * 512 + C0) * 1024,
                          As0, Bs0, As1, Bs1, acc);

  const float beta = beta_p[0];
  const int lane = threadIdx.x & 63, w = threadIdx.x >> 6;
  const int lr = lane & 15, lg = lane >> 4;
  const int wr = (w >> 1) * 64, wc = (w & 1) * 64;
  #pragma unroll
  for (int nf = 0; nf < 4; ++nf) {
    int col = C0 + wc + nf * 16 + lr;
    #pragma unroll
    for (int mf = 0; mf < 4; ++mf)
      #pragma unroll
      for (int i = 0; i < 4; i++) {
        int row = R0 + wr + mf * 16 + lg * 4 + i;
        float val = beta * acc[mf][nf][i] +
                    bf2f(vb[(size_t)(b * 1024 + row) * 512 + col]);
        outp[(size_t)(b * 1024 + row) * 512 + col] = val;
      }
  }
}

extern "C" void kernel_launch(void* const* d_in, const int* in_sizes, int n_in,
                              void* d_out, int out_size, void* d_ws, size_t ws_size,
                              hipStream_t stream) {
  (void)in_sizes; (void)n_in; (void)out_size;
  const float* x = (const float*)d_in[0];
  const float* Wq = (const float*)d_in[1];
  const float* bq = (const float*)d_in[2];
  const float* Wk = (const float*)d_in[3];
  const float* bk = (const float*)d_in[4];
  const float* Wv = (const float*)d_in[5];
  const float* bv = (const float*)d_in[6];
  const float* beta = (const float*)d_in[7];
  float* out = (float*)d_out;

  char* ws = (char*)d_ws;
  short* xb = (short*)(ws);                  // 32MB (dead after proj)
  short* wb = (short*)(ws + 33554432);       // 1.5MB
  short* qb = (short*)(ws + 35127296);       // 32MB
  short* kb = (short*)(ws + 68681728);       // 32MB
  short* vb = (short*)(ws + 102236160);      // 32MB
  short* eb = (short*)(ws + 135790592);      // 64MB (E, then P in-place)

  // fused-transpose path needs a vt region that does NOT alias xb (proj
  // reads xb while writing vt): place it after eb if ws allows.
  const int fuse = (ws_size >= 236453888ull) ? 1 : 0;
  short* vt = fuse ? (short*)(ws + 202899456) : xb;

  cvt_kernel<<<8192, 256, 0, stream>>>(x, xb, 2097152);
  cvt_w_kernel<<<384, 256, 0, stream>>>(Wq, Wk, Wv, wb);
  proj_kernel<<<3072, 256, 0, stream>>>(xb, wb, bq, bk, bv, qb, kb, vb, vt, fuse);
  if (!fuse) transpose_kernel<<<dim3(8, 16, 32), 256, 0, stream>>>(vb, vt);
  qk_kernel<<<2048, 256, 0, stream>>>(qb, kb, eb);
  softmax_kernel<<<8192, 256, 0, stream>>>(eb);
  pv_kernel<<<1024, 256, 0, stream>>>(eb, vt, vb, beta, out);
}

// Round 11
// 215.545 us; speedup vs baseline: 1.2116x; 1.1101x over previous
//
#include <hip/hip_runtime.h>
#include <hip/hip_bf16.h>

typedef short s8v __attribute__((ext_vector_type(8)));   // 8 bf16 = 16B (4 VGPR)
typedef float f4v __attribute__((ext_vector_type(4)));   // MFMA accum

#define MFMA_BF16(a, b, c) __builtin_amdgcn_mfma_f32_16x16x32_bf16((a), (b), (c), 0, 0, 0)

// async global->LDS, 16B per lane; LDS dest = wave-uniform base + lane*16
#define GLDS16(g, l) __builtin_amdgcn_global_load_lds( \
    (const __attribute__((address_space(1))) void*)(g), \
    (__attribute__((address_space(3))) void*)(l), 16, 0, 0)

__device__ __forceinline__ short f2bf(float f) {
  __hip_bfloat16 h = __float2bfloat16(f);
  return *reinterpret_cast<short*>(&h);
}
__device__ __forceinline__ float bf2f(short s) {
  __hip_bfloat16 h;
  *reinterpret_cast<short*>(&h) = s;
  return __bfloat162float(h);
}

// ---------------- fp32 -> bf16 conversion (x) ----------------
__global__ __launch_bounds__(256) void cvt_kernel(const float* __restrict__ in,
                                                  short* __restrict__ out, int n8) {
  int i = blockIdx.x * 256 + threadIdx.x;
  if (i >= n8) return;
  const float* p = in + (size_t)i * 8;
  float4 a = *(const float4*)p;
  float4 b = *(const float4*)(p + 4);
  s8v o;
  o[0] = f2bf(a.x); o[1] = f2bf(a.y); o[2] = f2bf(a.z); o[3] = f2bf(a.w);
  o[4] = f2bf(b.x); o[5] = f2bf(b.y); o[6] = f2bf(b.z); o[7] = f2bf(b.w);
  *(s8v*)(out + (size_t)i * 8) = o;
}

// ---------------- fp32 -> bf16 for the three W in one launch ----------------
__global__ __launch_bounds__(256) void cvt_w_kernel(const float* __restrict__ Wq,
                                                    const float* __restrict__ Wk,
                                                    const float* __restrict__ Wv,
                                                    short* __restrict__ out) {
  int i = blockIdx.x * 256 + threadIdx.x;      // 0..98303
  int mat = i >> 15, idx = i & 32767;          // 32768 groups of 8 per matrix
  const float* src = (mat == 0) ? Wq : (mat == 1) ? Wk : Wv;
  const float* p = src + (size_t)idx * 8;
  float4 a = *(const float4*)p;
  float4 b = *(const float4*)(p + 4);
  s8v o;
  o[0] = f2bf(a.x); o[1] = f2bf(a.y); o[2] = f2bf(a.z); o[3] = f2bf(a.w);
  o[4] = f2bf(b.x); o[5] = f2bf(b.y); o[6] = f2bf(b.z); o[7] = f2bf(b.w);
  *(s8v*)(out + (size_t)mat * 262144 + (size_t)idx * 8) = o;
}

// ------- 128x128 GEMM core, BK=64, 4 waves, 2-buffer ring, counted vmcnt ----
// (R8-validated schedule: vmcnt(8) keeps next tile's 8 loads in flight;
// mid-tile lgkmcnt(0)+barrier frees the buffer for stage(t+2); 2 blocks/CU
// supply cross-block TLP; XOR swizzle both-sides (rule 21), 0 bank conflicts.)
template<int KSTEPS, int ASTR, int BSTR>
__device__ __forceinline__ void mm_core(const short* __restrict__ Abase,
                                        const short* __restrict__ Bbase,
                                        short* As0, short* Bs0,
                                        short* As1, short* Bs1,
                                        f4v (&acc)[4][4]) {
  const int t = threadIdx.x;
  const int lane = t & 63, w = t >> 6;
  const int lr = lane & 15, lg = lane >> 4;
  const int wr = (w >> 1) * 64, wc = (w & 1) * 64;
  const int srcc = ((lane & 7) * 16) ^ ((lane >> 3) << 4);  // swizzled src col byte
  const int rstage = w * 32 + (lane >> 3);

  auto stage = [&](short* As, short* Bs, int kt) {
    #pragma unroll
    for (int j = 0; j < 4; ++j)
      GLDS16((const char*)(Abase + (size_t)(rstage + j * 8) * ASTR) + kt * 128 + srcc,
             (char*)As + (w * 32 + j * 8) * 128);
    #pragma unroll
    for (int j = 0; j < 4; ++j)
      GLDS16((const char*)(Bbase + (size_t)(rstage + j * 8) * BSTR) + kt * 128 + srcc,
             (char*)Bs + (w * 32 + j * 8) * 128);
  };

  stage(As0, Bs0, 0);
  if (KSTEPS > 1) stage(As1, Bs1, 1);
  short* Asc = As0; short* Bsc = Bs0;
  short* Asn = As1; short* Bsn = Bs1;

  for (int kt = 0; kt < KSTEPS; ++kt) {
    if (kt + 1 < KSTEPS) asm volatile("s_waitcnt vmcnt(8)" ::: "memory");
    else                 asm volatile("s_waitcnt vmcnt(0)" ::: "memory");
    __builtin_amdgcn_s_barrier();
    #pragma unroll
    for (int kk = 0; kk < 2; ++kk) {
      s8v af[4], bfr[4];
      #pragma unroll
      for (int mf = 0; mf < 4; ++mf)
        af[mf] = *(const s8v*)((const char*)Asc + (wr + mf * 16 + lr) * 128 +
                               ((kk * 64 + lg * 16) ^ ((lr & 7) << 4)));
      #pragma unroll
      for (int nf = 0; nf < 4; ++nf)
        bfr[nf] = *(const s8v*)((const char*)Bsc + (wc + nf * 16 + lr) * 128 +
                                ((kk * 64 + lg * 16) ^ ((lr & 7) << 4)));
      if (kk == 1) {
        asm volatile("s_waitcnt lgkmcnt(0)" ::: "memory");
        __builtin_amdgcn_s_barrier();
        if (kt + 2 < KSTEPS) stage(Asc, Bsc, kt + 2);
      }
      __builtin_amdgcn_s_setprio(1);
      #pragma unroll
      for (int mf = 0; mf < 4; ++mf)
        #pragma unroll
        for (int nf = 0; nf < 4; ++nf)
          acc[mf][nf] = MFMA_BF16(af[mf], bfr[nf], acc[mf][nf]);
      __builtin_amdgcn_s_setprio(0);
    }
    short* ta = Asc; Asc = Asn; Asn = ta;
    short* tb = Bsc; Bsc = Bsn; Bsn = tb;
  }
}

// ---------------- projections: y = x @ W^T + b ----------------
__global__ __launch_bounds__(256) void proj_kernel(
    const short* __restrict__ xb, const short* __restrict__ wb,
    const float* __restrict__ bq, const float* __restrict__ bk, const float* __restrict__ bv,
    short* __restrict__ qo, short* __restrict__ ko, short* __restrict__ vo) {
  const int bx = blockIdx.x;
  const int L = (bx & 7) * 384 + (bx >> 3);   // bijective XCD swizzle (3072 = 8*384)
  const int cb = L & 3, rb = (L >> 2) & 255, mat = L >> 10;
  const int R0 = rb * 128, C0 = cb * 128;
  const float* bias = (mat == 0) ? bq : (mat == 1) ? bk : bv;
  short* out = (mat == 0) ? qo : (mat == 1) ? ko : vo;

  __shared__ short As0[8192], Bs0[8192], As1[8192], Bs1[8192];
  f4v acc[4][4];
  #pragma unroll
  for (int i = 0; i < 4; i++)
    #pragma unroll
    for (int j = 0; j < 4; j++) acc[i][j] = (f4v){0.f, 0.f, 0.f, 0.f};

  mm_core<8, 512, 512>(xb + (size_t)R0 * 512,
                       wb + (size_t)mat * 512 * 512 + (size_t)C0 * 512,
                       As0, Bs0, As1, Bs1, acc);

  const int lane = threadIdx.x & 63, w = threadIdx.x >> 6;
  const int lr = lane & 15, lg = lane >> 4;
  const int wr = (w >> 1) * 64, wc = (w & 1) * 64;
  #pragma unroll
  for (int nf = 0; nf < 4; ++nf) {
    int col = C0 + wc + nf * 16 + lr;
    float bb = bias[col];
    #pragma unroll
    for (int mf = 0; mf < 4; ++mf)
      #pragma unroll
      for (int i = 0; i < 4; i++) {
        int row = R0 + wr + mf * 16 + lg * 4 + i;
        out[(size_t)row * 512 + col] = f2bf(acc[mf][nf][i] + bb);
      }
  }
}

// ---------------- v (B,C,N) -> v_t (B,N,C) ----------------
__global__ __launch_bounds__(256) void transpose_kernel(const short* __restrict__ v,
                                                        short* __restrict__ vt) {
  const int nb = blockIdx.x;
  const int cbk = blockIdx.y;
  const int b = blockIdx.z;
  __shared__ short tile[64 * 72];
  const int t = threadIdx.x;
  const int r = t >> 2, qd = t & 3;
  const short* src = v + (size_t)(b * 1024 + cbk * 64 + r) * 512 + nb * 64 + qd * 16;
  s8v v0 = *(const s8v*)src;
  s8v v1 = *(const s8v*)(src + 8);
  *(s8v*)&tile[r * 72 + qd * 16] = v0;
  *(s8v*)&tile[r * 72 + qd * 16 + 8] = v1;
  __syncthreads();
  s8v o0, o1;
  #pragma unroll
  for (int j = 0; j < 8; j++) o0[j] = tile[(qd * 16 + j) * 72 + r];
  #pragma unroll
  for (int j = 0; j < 8; j++) o1[j] = tile[(qd * 16 + 8 + j) * 72 + r];
  short* dst = vt + (size_t)(b * 512 + nb * 64 + r) * 1024 + cbk * 64 + qd * 16;
  *(s8v*)dst = o0;
  *(s8v*)(dst + 8) = o1;
}

// ---------------- E = Q @ K^T per batch ----------------
__global__ __launch_bounds__(256) void qk_kernel(const short* __restrict__ qb,
                                                 const short* __restrict__ kb,
                                                 short* __restrict__ eb) {
  const int bx = blockIdx.x;
  const int L = (bx & 7) * 256 + (bx >> 3);   // 2048 = 8*256
  const int rb = L & 7, cb = (L >> 3) & 7, b = L >> 6;
  const int R0 = rb * 128, C0 = cb * 128;

  __shared__ short As0[8192], Bs0[8192], As1[8192], Bs1[8192];
  f4v acc[4][4];
  #pragma unroll
  for (int i = 0; i < 4; i++)
    #pragma unroll
    for (int j = 0; j < 4; j++) acc[i][j] = (f4v){0.f, 0.f, 0.f, 0.f};

  mm_core<8, 512, 512>(qb + (size_t)(b * 1024 + R0) * 512,
                       kb + (size_t)(b * 1024 + C0) * 512,
                       As0, Bs0, As1, Bs1, acc);

  const int lane = threadIdx.x & 63, w = threadIdx.x >> 6;
  const int lr = lane & 15, lg = lane >> 4;
  const int wr = (w >> 1) * 64, wc = (w & 1) * 64;
  #pragma unroll
  for (int nf = 0; nf < 4; ++nf) {
    int col = C0 + wc + nf * 16 + lr;
    #pragma unroll
    for (int mf = 0; mf < 4; ++mf)
      #pragma unroll
      for (int i = 0; i < 4; i++) {
        int row = R0 + wr + mf * 16 + lg * 4 + i;
        eb[(size_t)(b * 1024 + row) * 1024 + col] = f2bf(acc[mf][nf][i]);
      }
  }
}

// ---------------- in-place row softmax (rows of 1024 bf16) ----------------
__global__ __launch_bounds__(256) void softmax_kernel(short* __restrict__ eb) {
  const int row = blockIdx.x * 4 + (threadIdx.x >> 6);
  const int lane = threadIdx.x & 63;
  short* p = eb + (size_t)row * 1024 + lane * 16;
  s8v a = *(const s8v*)p;
  s8v bvv = *(const s8v*)(p + 8);
  float v[16];
  #pragma unroll
  for (int j = 0; j < 8; j++) { v[j] = bf2f(a[j]); v[8 + j] = bf2f(bvv[j]); }
  float m = v[0];
  #pragma unroll
  for (int j = 1; j < 16; j++) m = fmaxf(m, v[j]);
  #pragma unroll
  for (int s = 1; s <= 32; s <<= 1) m = fmaxf(m, __shfl_xor(m, s));
  float l = 0.f;
  #pragma unroll
  for (int j = 0; j < 16; j++) { v[j] = __expf(v[j] - m); l += v[j]; }
  #pragma unroll
  for (int s = 1; s <= 32; s <<= 1) l += __shfl_xor(l, s);
  const float inv = 1.0f / l;
  s8v o0, o1;
  #pragma unroll
  for (int j = 0; j < 8; j++) { o0[j] = f2bf(v[j] * inv); o1[j] = f2bf(v[8 + j] * inv); }
  *(s8v*)p = o0;
  *(s8v*)(p + 8) = o1;
}

// ---------------- out = beta * (P @ V) + v ----------------
__global__ __launch_bounds__(256) void pv_kernel(const short* __restrict__ eb,
                                                 const short* __restrict__ vt,
                                                 const short* __restrict__ vb,
                                                 const float* __restrict__ beta_p,
                                                 float* __restrict__ outp) {
  const int bx = blockIdx.x;
  const int L = (bx & 7) * 128 + (bx >> 3);   // 1024 = 8*128
  const int cb = L & 3, rb = (L >> 2) & 7, b = L >> 5;
  const int R0 = rb * 128, C0 = cb * 128;

  __shared__ short As0[8192], Bs0[8192], As1[8192], Bs1[8192];
  f4v acc[4][4];
  #pragma unroll
  for (int i = 0; i < 4; i++)
    #pragma unroll
    for (int j = 0; j < 4; j++) acc[i][j] = (f4v){0.f, 0.f, 0.f, 0.f};

  mm_core<16, 1024, 1024>(eb + (size_t)(b * 1024 + R0) * 1024,
                          vt + (size_t)(b * 512 + C0) * 1024,
                          As0, Bs0, As1, Bs1, acc);

  const float beta = beta_p[0];
  const int lane = threadIdx.x & 63, w = threadIdx.x >> 6;
  const int lr = lane & 15, lg = lane >> 4;
  const int wr = (w >> 1) * 64, wc = (w & 1) * 64;
  #pragma unroll
  for (int nf = 0; nf < 4; ++nf) {
    int col = C0 + wc + nf * 16 + lr;
    #pragma unroll
    for (int mf = 0; mf < 4; ++mf)
      #pragma unroll
      for (int i = 0; i < 4; i++) {
        int row = R0 + wr + mf * 16 + lg * 4 + i;
        float val = beta * acc[mf][nf][i] +
                    bf2f(vb[(size_t)(b * 1024 + row) * 512 + col]);
        outp[(size_t)(b * 1024 + row) * 512 + col] = val;
      }
  }
}

extern "C" void kernel_launch(void* const* d_in, const int* in_sizes, int n_in,
                              void* d_out, int out_size, void* d_ws, size_t ws_size,
                              hipStream_t stream) {
  (void)in_sizes; (void)n_in; (void)out_size; (void)ws_size;
  const float* x = (const float*)d_in[0];
  const float* Wq = (const float*)d_in[1];
  const float* bq = (const float*)d_in[2];
  const float* Wk = (const float*)d_in[3];
  const float* bk = (const float*)d_in[4];
  const float* Wv = (const float*)d_in[5];
  const float* bv = (const float*)d_in[6];
  const float* beta = (const float*)d_in[7];
  float* out = (float*)d_out;

  char* ws = (char*)d_ws;
  short* xb = (short*)(ws);                  // 32MB, reused as v_t after proj
  short* wb = (short*)(ws + 33554432);       // 1.5MB
  short* qb = (short*)(ws + 35127296);       // 32MB
  short* kb = (short*)(ws + 68681728);       // 32MB
  short* vb = (short*)(ws + 102236160);      // 32MB
  short* eb = (short*)(ws + 135790592);      // 64MB (E, then P in-place)
  short* vt = xb;

  cvt_kernel<<<8192, 256, 0, stream>>>(x, xb, 2097152);
  cvt_w_kernel<<<384, 256, 0, stream>>>(Wq, Wk, Wv, wb);
  proj_kernel<<<3072, 256, 0, stream>>>(xb, wb, bq, bk, bv, qb, kb, vb);
  transpose_kernel<<<dim3(8, 16, 32), 256, 0, stream>>>(vb, vt);
  qk_kernel<<<2048, 256, 0, stream>>>(qb, kb, eb);
  softmax_kernel<<<8192, 256, 0, stream>>>(eb);
  pv_kernel<<<1024, 256, 0, stream>>>(eb, vt, vb, beta, out);
}

// Round 12
// 212.980 us; speedup vs baseline: 1.2262x; 1.0120x over previous
//
#include <hip/hip_runtime.h>
#include <hip/hip_bf16.h>

typedef short s8v __attribute__((ext_vector_type(8)));   // 8 bf16 = 16B (4 VGPR)
typedef float f4v __attribute__((ext_vector_type(4)));   // MFMA accum

#define MFMA_BF16(a, b, c) __builtin_amdgcn_mfma_f32_16x16x32_bf16((a), (b), (c), 0, 0, 0)

// async global->LDS, 16B per lane; LDS dest = wave-uniform base + lane*16
#define GLDS16(g, l) __builtin_amdgcn_global_load_lds( \
    (const __attribute__((address_space(1))) void*)(g), \
    (__attribute__((address_space(3))) void*)(l), 16, 0, 0)

__device__ __forceinline__ short f2bf(float f) {
  __hip_bfloat16 h = __float2bfloat16(f);
  return *reinterpret_cast<short*>(&h);
}
__device__ __forceinline__ float bf2f(short s) {
  __hip_bfloat16 h;
  *reinterpret_cast<short*>(&h) = s;
  return __bfloat162float(h);
}

// ------- fp32 -> bf16 for x (2M groups) AND Wq/Wk/Wv (3 x 32K groups) -------
// one launch: groups 0..2097151 = x; 2097152.. = weights (concat layout in wb)
__global__ __launch_bounds__(256) void cvt_all_kernel(
    const float* __restrict__ x, const float* __restrict__ Wq,
    const float* __restrict__ Wk, const float* __restrict__ Wv,
    short* __restrict__ xb, short* __restrict__ wb) {
  int i = blockIdx.x * 256 + threadIdx.x;     // 0..2195455
  const float* src;
  short* dst;
  if (i < 2097152) {
    src = x + (size_t)i * 8;
    dst = xb + (size_t)i * 8;
  } else {
    int j = i - 2097152;                      // 0..98303
    int mat = j >> 15, idx = j & 32767;
    const float* w = (mat == 0) ? Wq : (mat == 1) ? Wk : Wv;
    src = w + (size_t)idx * 8;
    dst = wb + (size_t)mat * 262144 + (size_t)idx * 8;
  }
  float4 a = *(const float4*)src;
  float4 b = *(const float4*)(src + 4);
  s8v o;
  o[0] = f2bf(a.x); o[1] = f2bf(a.y); o[2] = f2bf(a.z); o[3] = f2bf(a.w);
  o[4] = f2bf(b.x); o[5] = f2bf(b.y); o[6] = f2bf(b.z); o[7] = f2bf(b.w);
  *(s8v*)dst = o;
}

// ------- 128x128 GEMM core, BK=64, 4 waves, 2-buffer ring, counted vmcnt ----
// (R8-validated schedule: vmcnt(8) keeps next tile's 8 loads in flight;
// mid-tile lgkmcnt(0)+barrier frees the buffer for stage(t+2); 2 blocks/CU
// supply cross-block TLP; XOR swizzle both-sides (rule 21), 0 bank conflicts.)
template<int KSTEPS, int ASTR, int BSTR>
__device__ __forceinline__ void mm_core(const short* __restrict__ Abase,
                                        const short* __restrict__ Bbase,
                                        short* As0, short* Bs0,
                                        short* As1, short* Bs1,
                                        f4v (&acc)[4][4]) {
  const int t = threadIdx.x;
  const int lane = t & 63, w = t >> 6;
  const int lr = lane & 15, lg = lane >> 4;
  const int wr = (w >> 1) * 64, wc = (w & 1) * 64;
  const int srcc = ((lane & 7) * 16) ^ ((lane >> 3) << 4);  // swizzled src col byte
  const int rstage = w * 32 + (lane >> 3);

  auto stage = [&](short* As, short* Bs, int kt) {
    #pragma unroll
    for (int j = 0; j < 4; ++j)
      GLDS16((const char*)(Abase + (size_t)(rstage + j * 8) * ASTR) + kt * 128 + srcc,
             (char*)As + (w * 32 + j * 8) * 128);
    #pragma unroll
    for (int j = 0; j < 4; ++j)
      GLDS16((const char*)(Bbase + (size_t)(rstage + j * 8) * BSTR) + kt * 128 + srcc,
             (char*)Bs + (w * 32 + j * 8) * 128);
  };

  stage(As0, Bs0, 0);
  if (KSTEPS > 1) stage(As1, Bs1, 1);
  short* Asc = As0; short* Bsc = Bs0;
  short* Asn = As1; short* Bsn = Bs1;

  for (int kt = 0; kt < KSTEPS; ++kt) {
    if (kt + 1 < KSTEPS) asm volatile("s_waitcnt vmcnt(8)" ::: "memory");
    else                 asm volatile("s_waitcnt vmcnt(0)" ::: "memory");
    __builtin_amdgcn_s_barrier();
    #pragma unroll
    for (int kk = 0; kk < 2; ++kk) {
      s8v af[4], bfr[4];
      #pragma unroll
      for (int mf = 0; mf < 4; ++mf)
        af[mf] = *(const s8v*)((const char*)Asc + (wr + mf * 16 + lr) * 128 +
                               ((kk * 64 + lg * 16) ^ ((lr & 7) << 4)));
      #pragma unroll
      for (int nf = 0; nf < 4; ++nf)
        bfr[nf] = *(const s8v*)((const char*)Bsc + (wc + nf * 16 + lr) * 128 +
                                ((kk * 64 + lg * 16) ^ ((lr & 7) << 4)));
      if (kk == 1) {
        asm volatile("s_waitcnt lgkmcnt(0)" ::: "memory");
        __builtin_amdgcn_s_barrier();
        if (kt + 2 < KSTEPS) stage(Asc, Bsc, kt + 2);
      }
      __builtin_amdgcn_s_setprio(1);
      #pragma unroll
      for (int mf = 0; mf < 4; ++mf)
        #pragma unroll
        for (int nf = 0; nf < 4; ++nf)
          acc[mf][nf] = MFMA_BF16(af[mf], bfr[nf], acc[mf][nf]);
      __builtin_amdgcn_s_setprio(0);
    }
    short* ta = Asc; Asc = Asn; Asn = ta;
    short* tb = Bsc; Bsc = Bsn; Bsn = tb;
  }
}

// ---------------- projections: y = x @ W^T + b ----------------
__global__ __launch_bounds__(256) void proj_kernel(
    const short* __restrict__ xb, const short* __restrict__ wb,
    const float* __restrict__ bq, const float* __restrict__ bk, const float* __restrict__ bv,
    short* __restrict__ qo, short* __restrict__ ko, short* __restrict__ vo) {
  const int bx = blockIdx.x;
  const int L = (bx & 7) * 384 + (bx >> 3);   // bijective XCD swizzle (3072 = 8*384)
  const int cb = L & 3, rb = (L >> 2) & 255, mat = L >> 10;
  const int R0 = rb * 128, C0 = cb * 128;
  const float* bias = (mat == 0) ? bq : (mat == 1) ? bk : bv;
  short* out = (mat == 0) ? qo : (mat == 1) ? ko : vo;

  __shared__ short As0[8192], Bs0[8192], As1[8192], Bs1[8192];
  f4v acc[4][4];
  #pragma unroll
  for (int i = 0; i < 4; i++)
    #pragma unroll
    for (int j = 0; j < 4; j++) acc[i][j] = (f4v){0.f, 0.f, 0.f, 0.f};

  mm_core<8, 512, 512>(xb + (size_t)R0 * 512,
                       wb + (size_t)mat * 512 * 512 + (size_t)C0 * 512,
                       As0, Bs0, As1, Bs1, acc);

  const int lane = threadIdx.x & 63, w = threadIdx.x >> 6;
  const int lr = lane & 15, lg = lane >> 4;
  const int wr = (w >> 1) * 64, wc = (w & 1) * 64;
  #pragma unroll
  for (int nf = 0; nf < 4; ++nf) {
    int col = C0 + wc + nf * 16 + lr;
    float bb = bias[col];
    #pragma unroll
    for (int mf = 0; mf < 4; ++mf)
      #pragma unroll
      for (int i = 0; i < 4; i++) {
        int row = R0 + wr + mf * 16 + lg * 4 + i;
        out[(size_t)row * 512 + col] = f2bf(acc[mf][nf][i] + bb);
      }
  }
}

// ---------------- v (B,C,N) -> v_t (B,N,C) ----------------
__global__ __launch_bounds__(256) void transpose_kernel(const short* __restrict__ v,
                                                        short* __restrict__ vt) {
  const int nb = blockIdx.x;
  const int cbk = blockIdx.y;
  const int b = blockIdx.z;
  __shared__ short tile[64 * 72];
  const int t = threadIdx.x;
  const int r = t >> 2, qd = t & 3;
  const short* src = v + (size_t)(b * 1024 + cbk * 64 + r) * 512 + nb * 64 + qd * 16;
  s8v v0 = *(const s8v*)src;
  s8v v1 = *(const s8v*)(src + 8);
  *(s8v*)&tile[r * 72 + qd * 16] = v0;
  *(s8v*)&tile[r * 72 + qd * 16 + 8] = v1;
  __syncthreads();
  s8v o0, o1;
  #pragma unroll
  for (int j = 0; j < 8; j++) o0[j] = tile[(qd * 16 + j) * 72 + r];
  #pragma unroll
  for (int j = 0; j < 8; j++) o1[j] = tile[(qd * 16 + 8 + j) * 72 + r];
  short* dst = vt + (size_t)(b * 512 + nb * 64 + r) * 1024 + cbk * 64 + qd * 16;
  *(s8v*)dst = o0;
  *(s8v*)(dst + 8) = o1;
}

// ---------------- E = Q @ K^T per batch ----------------
__global__ __launch_bounds__(256) void qk_kernel(const short* __restrict__ qb,
                                                 const short* __restrict__ kb,
                                                 short* __restrict__ eb) {
  const int bx = blockIdx.x;
  const int L = (bx & 7) * 256 + (bx >> 3);   // 2048 = 8*256
  const int rb = L & 7, cb = (L >> 3) & 7, b = L >> 6;
  const int R0 = rb * 128, C0 = cb * 128;

  __shared__ short As0[8192], Bs0[8192], As1[8192], Bs1[8192];
  f4v acc[4][4];
  #pragma unroll
  for (int i = 0; i < 4; i++)
    #pragma unroll
    for (int j = 0; j < 4; j++) acc[i][j] = (f4v){0.f, 0.f, 0.f, 0.f};

  mm_core<8, 512, 512>(qb + (size_t)(b * 1024 + R0) * 512,
                       kb + (size_t)(b * 1024 + C0) * 512,
                       As0, Bs0, As1, Bs1, acc);

  const int lane = threadIdx.x & 63, w = threadIdx.x >> 6;
  const int lr = lane & 15, lg = lane >> 4;
  const int wr = (w >> 1) * 64, wc = (w & 1) * 64;
  #pragma unroll
  for (int nf = 0; nf < 4; ++nf) {
    int col = C0 + wc + nf * 16 + lr;
    #pragma unroll
    for (int mf = 0; mf < 4; ++mf)
      #pragma unroll
      for (int i = 0; i < 4; i++) {
        int row = R0 + wr + mf * 16 + lg * 4 + i;
        eb[(size_t)(b * 1024 + row) * 1024 + col] = f2bf(acc[mf][nf][i]);
      }
  }
}

// ---------------- in-place row softmax (rows of 1024 bf16) ----------------
__global__ __launch_bounds__(256) void softmax_kernel(short* __restrict__ eb) {
  const int row = blockIdx.x * 4 + (threadIdx.x >> 6);
  const int lane = threadIdx.x & 63;
  short* p = eb + (size_t)row * 1024 + lane * 16;
  s8v a = *(const s8v*)p;
  s8v bvv = *(const s8v*)(p + 8);
  float v[16];
  #pragma unroll
  for (int j = 0; j < 8; j++) { v[j] = bf2f(a[j]); v[8 + j] = bf2f(bvv[j]); }
  float m = v[0];
  #pragma unroll
  for (int j = 1; j < 16; j++) m = fmaxf(m, v[j]);
  #pragma unroll
  for (int s = 1; s <= 32; s <<= 1) m = fmaxf(m, __shfl_xor(m, s));
  float l = 0.f;
  #pragma unroll
  for (int j = 0; j < 16; j++) { v[j] = __expf(v[j] - m); l += v[j]; }
  #pragma unroll
  for (int s = 1; s <= 32; s <<= 1) l += __shfl_xor(l, s);
  const float inv = 1.0f / l;
  s8v o0, o1;
  #pragma unroll
  for (int j = 0; j < 8; j++) { o0[j] = f2bf(v[j] * inv); o1[j] = f2bf(v[8 + j] * inv); }
  *(s8v*)p = o0;
  *(s8v*)(p + 8) = o1;
}

// ---------------- out = beta * (P @ V) + v ----------------
__global__ __launch_bounds__(256) void pv_kernel(const short* __restrict__ eb,
                                                 const short* __restrict__ vt,
                                                 const short* __restrict__ vb,
                                                 const float* __restrict__ beta_p,
                                                 float* __restrict__ outp) {
  const int bx = blockIdx.x;
  const int L = (bx & 7) * 128 + (bx >> 3);   // 1024 = 8*128
  const int cb = L & 3, rb = (L >> 2) & 7, b = L >> 5;
  const int R0 = rb * 128, C0 = cb * 128;

  __shared__ short As0[8192], Bs0[8192], As1[8192], Bs1[8192];
  f4v acc[4][4];
  #pragma unroll
  for (int i = 0; i < 4; i++)
    #pragma unroll
    for (int j = 0; j < 4; j++) acc[i][j] = (f4v){0.f, 0.f, 0.f, 0.f};

  mm_core<16, 1024, 1024>(eb + (size_t)(b * 1024 + R0) * 1024,
                          vt + (size_t)(b * 512 + C0) * 1024,
                          As0, Bs0, As1, Bs1, acc);

  const float beta = beta_p[0];
  const int lane = threadIdx.x & 63, w = threadIdx.x >> 6;
  const int lr = lane & 15, lg = lane >> 4;
  const int wr = (w >> 1) * 64, wc = (w & 1) * 64;
  #pragma unroll
  for (int nf = 0; nf < 4; ++nf) {
    int col = C0 + wc + nf * 16 + lr;
    #pragma unroll
    for (int mf = 0; mf < 4; ++mf)
      #pragma unroll
      for (int i = 0; i < 4; i++) {
        int row = R0 + wr + mf * 16 + lg * 4 + i;
        float val = beta * acc[mf][nf][i] +
                    bf2f(vb[(size_t)(b * 1024 + row) * 512 + col]);
        outp[(size_t)(b * 1024 + row) * 512 + col] = val;
      }
  }
}

extern "C" void kernel_launch(void* const* d_in, const int* in_sizes, int n_in,
                              void* d_out, int out_size, void* d_ws, size_t ws_size,
                              hipStream_t stream) {
  (void)in_sizes; (void)n_in; (void)out_size; (void)ws_size;
  const float* x = (const float*)d_in[0];
  const float* Wq = (const float*)d_in[1];
  const float* bq = (const float*)d_in[2];
  const float* Wk = (const float*)d_in[3];
  const float* bk = (const float*)d_in[4];
  const float* Wv = (const float*)d_in[5];
  const float* bv = (const float*)d_in[6];
  const float* beta = (const float*)d_in[7];
  float* out = (float*)d_out;

  char* ws = (char*)d_ws;
  short* xb = (short*)(ws);                  // 32MB, reused as v_t after proj
  short* wb = (short*)(ws + 33554432);       // 1.5MB
  short* qb = (short*)(ws + 35127296);       // 32MB
  short* kb = (short*)(ws + 68681728);       // 32MB
  short* vb = (short*)(ws + 102236160);      // 32MB
  short* eb = (short*)(ws + 135790592);      // 64MB (E, then P in-place)
  short* vt = xb;

  cvt_all_kernel<<<8576, 256, 0, stream>>>(x, Wq, Wk, Wv, xb, wb);
  proj_kernel<<<3072, 256, 0, stream>>>(xb, wb, bq, bk, bv, qb, kb, vb);
  transpose_kernel<<<dim3(8, 16, 32), 256, 0, stream>>>(vb, vt);
  qk_kernel<<<2048, 256, 0, stream>>>(qb, kb, eb);
  softmax_kernel<<<8192, 256, 0, stream>>>(eb);
  pv_kernel<<<1024, 256, 0, stream>>>(eb, vt, vb, beta, out);
}